// Round 1
// baseline (459.072 us; speedup 1.0000x reference)
//
#include <hip/hip_runtime.h>
#include <hip/hip_bf16.h>
#include <stdint.h>

#define B_    64
#define S_    2048
#define ENC_  512
#define ATTN_ 256

typedef __bf16 bf16;
typedef bf16  bf16x8 __attribute__((ext_vector_type(8)));
typedef float f32x4  __attribute__((ext_vector_type(4)));

__device__ __forceinline__ float fexp2(float x) {
#if __has_builtin(__builtin_amdgcn_exp2f)
    return __builtin_amdgcn_exp2f(x);
#else
    return exp2f(x);
#endif
}
__device__ __forceinline__ float frcp(float x) {
#if __has_builtin(__builtin_amdgcn_rcpf)
    return __builtin_amdgcn_rcpf(x);
#else
    return 1.0f / x;
#endif
}
// tanh(x) = 1 - 2/(e^{2x}+1); overflow-safe (exp2->inf => 1, ->0 => -1)
__device__ __forceinline__ float fast_tanh(float x) {
    float e = fexp2(x * 2.8853900817779268f);
    return 1.0f - 2.0f * frcp(e + 1.0f);
}

__device__ __forceinline__ void async_copy16(const void* g, void* l) {
#if __has_builtin(__builtin_amdgcn_global_load_lds)
    __builtin_amdgcn_global_load_lds(
        (__attribute__((address_space(1))) void*)(g),
        (__attribute__((address_space(3))) void*)(l), 16, 0, 0);
#else
    // fallback: plain copy
    *(uint4*)l = *(const uint4*)g;
#endif
}

// ---------------- setup: W_enc [512][256] fp32 -> WT [256][512] bf16 -------
__global__ __launch_bounds__(256) void k_prep(const float* __restrict__ W_enc,
                                              bf16* __restrict__ WT) {
    int idx = blockIdx.x * 256 + threadIdx.x;   // 0..131071
    int n = idx >> 9;        // /512
    int k = idx & 511;
    WT[idx] = (bf16)W_enc[k * ATTN_ + n];       // coalesced writes
}

// ---------------- setup: dec_proj[b][a] = dec_state[b] @ W_dec -------------
__global__ __launch_bounds__(256) void k_decproj(const float* __restrict__ dec_state,
                                                 const float* __restrict__ W_dec,
                                                 float* __restrict__ dp) {
    int b = blockIdx.x;
    int a = threadIdx.x;
    const float* ds = dec_state + b * 512;
    float acc = 0.f;
#pragma unroll 8
    for (int d = 0; d < 512; ++d)
        acc += ds[d] * W_dec[d * ATTN_ + a];
    dp[b * ATTN_ + a] = acc;
}

// ---------------- scores: fused GEMM(M=131072,K=512,N=256) + tanh.v --------
// block = 64 rows x 256 cols, 4 waves in 2x2 (each wave 32 rows x 128 cols)
__global__ __launch_bounds__(256) void k_scores(
    const float* __restrict__ enc,    // [131072][512]
    const bf16*  __restrict__ WT,     // [256][512] (n-major)
    const float* __restrict__ dp,     // [64][256]
    const float* __restrict__ v,      // [256]
    float* __restrict__ out_scores)   // [131072]
{
    __shared__ __align__(16) bf16 As[64 * 32];    // [row][k], 16B-chunk swizzled
    __shared__ __align__(16) bf16 Bs[256 * 32];   // [n][k],  16B-chunk swizzled
    __shared__ float partial[4][32];

    const int tid  = threadIdx.x;
    const int wave = tid >> 6;
    const int lane = tid & 63;
    const int m0   = blockIdx.x * 64;
    const int b    = m0 >> 11;              // row / 2048

    const int mrow0 = (wave >> 1) * 32;
    const int ncol0 = (wave & 1) * 128;
    const int l15 = lane & 15;
    const int q   = lane >> 4;

    // preload dp & v for this lane's 8 column groups
    float dpv[8], vv[8];
#pragma unroll
    for (int nt = 0; nt < 8; ++nt) {
        int col = ncol0 + nt * 16 + l15;
        dpv[nt] = dp[b * 256 + col];
        vv[nt]  = v[col];
    }

    const f32x4 zero4 = {0.f, 0.f, 0.f, 0.f};
    f32x4 acc[2][8];
#pragma unroll
    for (int mt = 0; mt < 2; ++mt)
#pragma unroll
        for (int nt = 0; nt < 8; ++nt)
            acc[mt][nt] = zero4;

    // A staging: thread t -> row t>>2, k-chunk (t&3)*8
    const int arow = tid >> 2;
    const int ac   = tid & 3;
    const int aphys = ac ^ ((arow >> 1) & 3);          // 16B-chunk swizzle
    const float* ag = enc + (size_t)(m0 + arow) * 512 + ac * 8;

    // B staging: round r -> n = r*64 + (t>>2); forced LDS dst = base + 16*t
    const int bn4 = tid >> 2;
    const int bc  = tid & 3;

    for (int ks = 0; ks < 16; ++ks) {
        // ---- stage A (fp32 -> bf16, swizzled ds_write_b128) ----
        float4 f0 = *(const float4*)(ag + ks * 32);
        float4 f1 = *(const float4*)(ag + ks * 32 + 4);
        bf16x8 av;
        av[0]=(bf16)f0.x; av[1]=(bf16)f0.y; av[2]=(bf16)f0.z; av[3]=(bf16)f0.w;
        av[4]=(bf16)f1.x; av[5]=(bf16)f1.y; av[6]=(bf16)f1.z; av[7]=(bf16)f1.w;
        *(bf16x8*)(&As[arow * 32 + aphys * 8]) = av;

        // ---- stage B via global_load_lds (dst forced = base + lane*16) ----
#pragma unroll
        for (int r = 0; r < 4; ++r) {
            int n = r * 64 + bn4;
            int c = bc ^ ((n >> 1) & 3);               // fetch the chunk that
            const bf16* src = WT + (size_t)n * 512 + ks * 32 + c * 8;
            async_copy16(src, &Bs[r * 2048 + tid * 8]); // lands in slot t
        }
        __syncthreads();

        // ---- compute: 2 a_frags, 8 b_frags, 16 MFMAs ----
        bf16x8 af[2];
#pragma unroll
        for (int mt = 0; mt < 2; ++mt) {
            int row = mrow0 + mt * 16 + l15;
            int p = q ^ ((row >> 1) & 3);
            af[mt] = *(const bf16x8*)(&As[row * 32 + p * 8]);
        }
#pragma unroll
        for (int nt = 0; nt < 8; ++nt) {
            int n = ncol0 + nt * 16 + l15;
            int p = q ^ ((n >> 1) & 3);
            bf16x8 bfr = *(const bf16x8*)(&Bs[n * 32 + p * 8]);
            acc[0][nt] = __builtin_amdgcn_mfma_f32_16x16x32_bf16(af[0], bfr, acc[0][nt], 0, 0, 0);
            acc[1][nt] = __builtin_amdgcn_mfma_f32_16x16x32_bf16(af[1], bfr, acc[1][nt], 0, 0, 0);
        }
        __syncthreads();
    }

    // ---- epilogue: scores[row] = sum_col tanh(C + dp) * v ----
    // C/D layout: row_local = q*4 + reg, col = l15 (+16*nt)
    float ps[2][4];
#pragma unroll
    for (int mt = 0; mt < 2; ++mt)
#pragma unroll
        for (int r = 0; r < 4; ++r) {
            float s = 0.f;
#pragma unroll
            for (int nt = 0; nt < 8; ++nt)
                s += fast_tanh(acc[mt][nt][r] + dpv[nt]) * vv[nt];
            // reduce across the 16 lanes sharing q (butterfly, width 16)
            s += __shfl_xor(s, 1, 16);
            s += __shfl_xor(s, 2, 16);
            s += __shfl_xor(s, 4, 16);
            s += __shfl_xor(s, 8, 16);
            ps[mt][r] = s;
        }
    if (l15 == 0) {
#pragma unroll
        for (int mt = 0; mt < 2; ++mt)
#pragma unroll
            for (int r = 0; r < 4; ++r)
                partial[wave][mt * 16 + q * 4 + r] = ps[mt][r];
    }
    __syncthreads();
    if (tid < 64) {
        int half = tid >> 5;           // rows 0-31 -> waves 0+1, 32-63 -> 2+3
        int rr = tid & 31;
        out_scores[m0 + tid] = partial[half * 2][rr] + partial[half * 2 + 1][rr];
    }
}

// ---------------- softmax over S per batch, in place in d_out --------------
__global__ __launch_bounds__(256) void k_softmax(float* __restrict__ attn) {
    int b = blockIdx.x;
    float* s = attn + b * 2048;
    __shared__ float red[256];
    int tid = threadIdx.x;

    float x[8];
    float mx = -1e30f;
#pragma unroll
    for (int i = 0; i < 8; ++i) { x[i] = s[tid + 256 * i]; mx = fmaxf(mx, x[i]); }
    red[tid] = mx;
    __syncthreads();
    for (int off = 128; off > 0; off >>= 1) {
        if (tid < off) red[tid] = fmaxf(red[tid], red[tid + off]);
        __syncthreads();
    }
    mx = red[0];
    __syncthreads();

    float e[8];
    float lsum = 0.f;
#pragma unroll
    for (int i = 0; i < 8; ++i) { e[i] = fexp2((x[i] - mx) * 1.4426950408889634f); lsum += e[i]; }
    red[tid] = lsum;
    __syncthreads();
    for (int off = 128; off > 0; off >>= 1) {
        if (tid < off) red[tid] += red[tid + off];
        __syncthreads();
    }
    float inv = 1.0f / red[0];
#pragma unroll
    for (int i = 0; i < 8; ++i) s[tid + 256 * i] = e[i] * inv;
}

// ---------------- context[b][e] = sum_s attn[b][s] * enc[b][s][e] ----------
// grid: 64 b x 16 e-chunks(32); block: 8 s-groups x 32 e-lanes
__global__ __launch_bounds__(256) void k_context(const float* __restrict__ enc,
                                                 const float* __restrict__ attn,
                                                 float* __restrict__ ctx) {
    int b     = blockIdx.x >> 4;
    int chunk = blockIdx.x & 15;
    int tid = threadIdx.x;
    int e  = chunk * 32 + (tid & 31);
    int sg = tid >> 5;                      // 0..7
    const float* eb = enc + (size_t)b * 2048 * 512;
    const float* w  = attn + b * 2048;
    float acc = 0.f;
    // reverse order: tail of enc is most-recently streamed through L3
#pragma unroll 8
    for (int s = 2047 - sg; s >= 0; s -= 8)
        acc += w[s] * eb[(size_t)s * 512 + e];
    __shared__ float red[256];
    red[tid] = acc;
    __syncthreads();
    if (tid < 32) {
        float t = red[tid] + red[tid + 32] + red[tid + 64] + red[tid + 96]
                + red[tid + 128] + red[tid + 160] + red[tid + 192] + red[tid + 224];
        ctx[b * 512 + chunk * 32 + tid] = t;
    }
}

extern "C" void kernel_launch(void* const* d_in, const int* in_sizes, int n_in,
                              void* d_out, int out_size, void* d_ws, size_t ws_size,
                              hipStream_t stream) {
    const float* enc       = (const float*)d_in[0];
    const float* dec_state = (const float*)d_in[1];
    const float* W_enc     = (const float*)d_in[2];
    const float* W_dec     = (const float*)d_in[3];
    const float* v         = (const float*)d_in[4];

    float* ctx  = (float*)d_out;                 // [64,512]
    float* attn = (float*)d_out + 64 * 512;      // [64,2048] (scores, then softmax in place)

    // workspace: WT bf16 [256*512] = 256KB, dp fp32 [64*256] = 64KB
    char* ws = (char*)d_ws;
    bf16*  WT = (bf16*)ws;
    float* dp = (float*)(ws + 256 * 512 * sizeof(bf16));

    k_prep   <<<512, 256, 0, stream>>>(W_enc, WT);
    k_decproj<<<64, 256, 0, stream>>>(dec_state, W_dec, dp);
    k_scores <<<2048, 256, 0, stream>>>(enc, WT, dp, v, attn);
    k_softmax<<<64, 256, 0, stream>>>(attn);
    k_context<<<1024, 256, 0, stream>>>(enc, attn, ctx);
}